// Round 12
// baseline (23.146 us; speedup 1.0000x reference)
//
#include <hip/hip_runtime.h>

// VectorGauntTensorProduct — factored algebraic collapse, 2-launch structure.
// r12 = r11 with stages A+B FUSED: the thread that computes the 9 per-block
// partials Z[row,t,b] (registers) immediately contracts them with V and writes
// Zout — no Z LDS buffer, no A->B barrier, no Z re-read traffic.
//
// T[t,pq]  = sum_g wq[g] Yin[g,s] Yin[g,sp] Yout[g,t]       (25x100, block-padded)
// V[lt,b,d]= sum_c Wx[ls,c] Wy[lsp,c] Wz[lt,c,d]            (stride-292 rows!)
// P[row,pq]= x[n,a,s] y[n,b,sp] - x[n,b,s] y[n,a,sp]        (row = ni*3+v)
// out[n,d,v,t] = sum_b (sum_{pq in b} P[row,pq] T[t,pq]) V[l(t),b,d]
//
// Padded block layout: block b = ls*3+lsp, real sizes {1,3,5,3,9,15,5,15,25}
// padded to /4: {4,4,8,4,12,16,8,16,28}, starts {0,4,8,16,20,32,48,56,72}, tot 100.
// Pads are 0.0 in BOTH T and P -> contribute nothing.
// V row stride 292 (=9*32+4): 292%32=4, so lanes with different lt hit
// different banks on the fused f4 V-reads (stride 288 would alias bank 0).
//
// BUG HISTORY: r4 Zout/Vs overlay race; r4-r6 `if(tid<360)` staging with 256
// threads left Vs[1024:1440) unstaged (STRIDED loops only). r9->r10: direct
// scatter stores amplify L2 write sectors ~16x -> stage output in LDS, store
// coalesced f4. r10->r11: keep LDS <= 40KB for 4 blocks/CU, one latency round.

#define GG 380

// decode padded index pq (<100) -> (s, sp); false if pad slot
__device__ __forceinline__ bool decode2(int pq, int& s, int& sp) {
    int b, off;
    if (pq < 16) {
        if (pq < 4)       { b = 0; off = pq; }
        else if (pq < 8)  { b = 1; off = pq - 4; }
        else              { b = 2; off = pq - 8; }
    } else if (pq < 48) {
        if (pq < 20)      { b = 3; off = pq - 16; }
        else if (pq < 32) { b = 4; off = pq - 20; }
        else              { b = 5; off = pq - 32; }
    } else {
        if (pq < 56)      { b = 6; off = pq - 48; }
        else if (pq < 72) { b = 7; off = pq - 56; }
        else              { b = 8; off = pq - 72; }
    }
    int ls = b / 3, lsp = b % 3, w = 2 * lsp + 1;
    if (off >= (2 * ls + 1) * w) return false;
    s  = ls * ls + off / w;
    sp = lsp * lsp + off % w;
    return true;
}

// ---- precomp (single kernel): T wave-per-entry + V (V rows now stride 292)
__global__ __launch_bounds__(256) void precomp(const float* __restrict__ Wx,
                                               const float* __restrict__ Wy,
                                               const float* __restrict__ Wz,
                                               const float* __restrict__ Yin,
                                               const float* __restrict__ Yout,
                                               const float* __restrict__ wq,
                                               float* __restrict__ Tg,
                                               float* __restrict__ Vg) {
    int bid = blockIdx.x;
    if (bid < 625) {
        int W = bid * 4 + (threadIdx.x >> 6);     // 0..2499, = t*100 + pq
        int lane = threadIdx.x & 63;
        int t = W / 100, pq = W % 100;
        int s, sp;
        float acc = 0.f;
        if (decode2(pq, s, sp)) {
#pragma unroll
            for (int i = 0; i < 6; ++i) {
                int g = lane + 64 * i;
                if (g < GG)
                    acc = fmaf(wq[g] * Yin[g * 9 + s],
                               Yin[g * 9 + sp] * Yout[g * 25 + t], acc);
            }
        }
#pragma unroll
        for (int m = 32; m; m >>= 1) acc += __shfl_xor(acc, m, 64);
        if (lane == 0) Tg[W] = acc;               // pads write 0
    } else {
        int idx = (bid - 625) * 256 + threadIdx.x;
        if (idx < 1460) {                          // 5 rows * 292 (incl pads)
            int lt = idx / 292, r = idx % 292;
            float acc = 0.f;
            if (r < 288) {
                int b = r / 32, d = r % 32;
                int ls = b / 3, lsp = b % 3;
                for (int c = 0; c < 32; ++c)
                    acc = fmaf(Wx[ls * 32 + c] * Wy[lsp * 32 + c],
                               Wz[lt * 1024 + c * 32 + d], acc);
            }
            Vg[idx] = acc;                         // pad slots -> 0
        }
    }
}

// ---- main: 2 samples/block, 1024 blocks, 256 threads, LDS 38.3 KB, no overlays.
// LDS floats: xs[0,108)* ys[108,216)* Ps[216,816) Ts[816,3316) Vs[3316,4776)
//             Zout[4776,9576)   (*54 used each)
__global__ __launch_bounds__(256) void gaunt_main(const float* __restrict__ x,
                                                  const float* __restrict__ y,
                                                  const float* __restrict__ Tg,
                                                  const float* __restrict__ Vg,
                                                  float* __restrict__ out) {
    __shared__ __align__(16) float smem[9576];
    float* xs   = smem;            // 54 used
    float* ys   = smem + 108;      // 54 used
    float* Ps   = smem + 216;      // 6*100
    float* Ts   = smem + 816;      // 25*100
    float* Vs   = smem + 3316;     // 5*292
    float* Zout = smem + 4776;     // 4800

    const int tid = threadIdx.x;
    const int n0 = blockIdx.x * 2;

    if (tid < 54)       xs[tid]      = x[n0 * 27 + tid];
    else if (tid < 108) ys[tid - 54] = y[n0 * 27 + tid - 54];
    for (int i = tid; i < 625; i += 256)            // Ts: 2500 floats
        ((float4*)Ts)[i] = ((const float4*)Tg)[i];
    for (int i = tid; i < 365; i += 256)            // Vs: 1460 floats (strided)
        ((float4*)Vs)[i] = ((const float4*)Vg)[i];
    __syncthreads();

    // P[row][100], pads zero
    for (int idx = tid; idx < 600; idx += 256) {
        int row = idx / 100, pq = idx % 100;
        float v = 0.f;
        int s, sp;
        if (decode2(pq, s, sp)) {
            int ni = row / 3, vv = row % 3;
            int a = (vv == 0) ? 1 : ((vv == 1) ? 2 : 0);
            int b = (vv == 0) ? 2 : ((vv == 1) ? 0 : 1);
            v = xs[ni * 27 + a * 9 + s] * ys[ni * 27 + b * 9 + sp]
              - xs[ni * 27 + b * 9 + s] * ys[ni * 27 + a * 9 + sp];
        }
        Ps[idx] = v;
    }
    __syncthreads();

    // FUSED stage A+B: thread (t,row) computes 9 reg partials, contracts with V,
    // writes 32 outputs (all d) to Zout. No Z buffer, no extra barrier.
#define DOT4(c, accv) { float4 pv = P4[c], tv = T4[c];                      \
        accv = fmaf(pv.x, tv.x, accv); accv = fmaf(pv.y, tv.y, accv);       \
        accv = fmaf(pv.z, tv.z, accv); accv = fmaf(pv.w, tv.w, accv); }
    if (tid < 150) {
        const int t = tid / 6, row = tid % 6;
        const float4* P4 = (const float4*)(Ps + row * 100);
        const float4* T4 = (const float4*)(Ts + t * 100);
        float a0 = 0.f, a1 = 0.f, a2 = 0.f, a3 = 0.f, a4 = 0.f,
              a5 = 0.f, a6 = 0.f, a7 = 0.f, a8 = 0.f;
        DOT4(0, a0)
        DOT4(1, a1)
        DOT4(2, a2)  DOT4(3, a2)
        DOT4(4, a3)
        DOT4(5, a4)  DOT4(6, a4)  DOT4(7, a4)
        DOT4(8, a5)  DOT4(9, a5)  DOT4(10, a5) DOT4(11, a5)
        DOT4(12, a6) DOT4(13, a6)
        DOT4(14, a7) DOT4(15, a7) DOT4(16, a7) DOT4(17, a7)
        DOT4(18, a8) DOT4(19, a8) DOT4(20, a8) DOT4(21, a8)
        DOT4(22, a8) DOT4(23, a8) DOT4(24, a8)

        const int lt = (t >= 16) ? 4 : (t >= 9) ? 3 : (t >= 4) ? 2
                     : (t >= 1) ? 1 : 0;
        const float* vbase = Vs + lt * 292;        // [b][32], stride-292 rows
        const int zo = (row / 3) * 2400 + (row % 3) * 25 + t;
#pragma unroll
        for (int dq = 0; dq < 8; ++dq) {
            const float4 w0 = *(const float4*)(vbase +   0 + dq * 4);
            const float4 w1 = *(const float4*)(vbase +  32 + dq * 4);
            const float4 w2 = *(const float4*)(vbase +  64 + dq * 4);
            const float4 w3 = *(const float4*)(vbase +  96 + dq * 4);
            const float4 w4 = *(const float4*)(vbase + 128 + dq * 4);
            const float4 w5 = *(const float4*)(vbase + 160 + dq * 4);
            const float4 w6 = *(const float4*)(vbase + 192 + dq * 4);
            const float4 w7 = *(const float4*)(vbase + 224 + dq * 4);
            const float4 w8 = *(const float4*)(vbase + 256 + dq * 4);
            float o0 = a8 * w8.x, o1 = a8 * w8.y, o2 = a8 * w8.z, o3 = a8 * w8.w;
            o0 = fmaf(a0, w0.x, o0); o1 = fmaf(a0, w0.y, o1);
            o2 = fmaf(a0, w0.z, o2); o3 = fmaf(a0, w0.w, o3);
            o0 = fmaf(a1, w1.x, o0); o1 = fmaf(a1, w1.y, o1);
            o2 = fmaf(a1, w1.z, o2); o3 = fmaf(a1, w1.w, o3);
            o0 = fmaf(a2, w2.x, o0); o1 = fmaf(a2, w2.y, o1);
            o2 = fmaf(a2, w2.z, o2); o3 = fmaf(a2, w2.w, o3);
            o0 = fmaf(a3, w3.x, o0); o1 = fmaf(a3, w3.y, o1);
            o2 = fmaf(a3, w3.z, o2); o3 = fmaf(a3, w3.w, o3);
            o0 = fmaf(a4, w4.x, o0); o1 = fmaf(a4, w4.y, o1);
            o2 = fmaf(a4, w4.z, o2); o3 = fmaf(a4, w4.w, o3);
            o0 = fmaf(a5, w5.x, o0); o1 = fmaf(a5, w5.y, o1);
            o2 = fmaf(a5, w5.z, o2); o3 = fmaf(a5, w5.w, o3);
            o0 = fmaf(a6, w6.x, o0); o1 = fmaf(a6, w6.y, o1);
            o2 = fmaf(a6, w6.z, o2); o3 = fmaf(a6, w6.w, o3);
            o0 = fmaf(a7, w7.x, o0); o1 = fmaf(a7, w7.y, o1);
            o2 = fmaf(a7, w7.z, o2); o3 = fmaf(a7, w7.w, o3);
            Zout[zo + (dq * 4 + 0) * 75] = o0;
            Zout[zo + (dq * 4 + 1) * 75] = o1;
            Zout[zo + (dq * 4 + 2) * 75] = o2;
            Zout[zo + (dq * 4 + 3) * 75] = o3;
        }
    }
#undef DOT4
    __syncthreads();

    // coalesced copy-out: 4800 floats = 1200 float4, contiguous per block
    float4* og = (float4*)(out + (size_t)n0 * 2400);
    const float4* zo4 = (const float4*)Zout;
    for (int i = tid; i < 1200; i += 256) og[i] = zo4[i];
}

extern "C" void kernel_launch(void* const* d_in, const int* in_sizes, int n_in,
                              void* d_out, int out_size, void* d_ws, size_t ws_size,
                              hipStream_t stream) {
    const float* x    = (const float*)d_in[0];
    const float* y    = (const float*)d_in[1];
    const float* Wx   = (const float*)d_in[2];
    const float* Wy   = (const float*)d_in[3];
    const float* Wz   = (const float*)d_in[4];
    const float* Yin  = (const float*)d_in[5];
    const float* Yout = (const float*)d_in[6];
    const float* wq   = (const float*)d_in[7];
    float* out = (float*)d_out;

    float* Tg = (float*)d_ws;        // 25*100 = 2500 floats
    float* Vg = Tg + 2500;           // 5*292 = 1460 floats (16B-aligned)

    precomp<<<631, 256, 0, stream>>>(Wx, Wy, Wz, Yin, Yout, wq, Tg, Vg);
    gaunt_main<<<1024, 256, 0, stream>>>(x, y, Tg, Vg, out);
}